// Round 5
// baseline (1504.344 us; speedup 1.0000x reference)
//
#include <hip/hip_runtime.h>
#include <stdint.h>

// GraphConv: out = fxp( Drow^-1/2 * A^T * (Dcol^-1/2-scaled fxp(x@w)) + b )
// A is a 16384x16384 dense 0/1 fp32 matrix, density 0.001 (~268K nonzeros).
// One streaming pass over A (1.073 GB, HBM floor ~171us) builds degrees +
// per-destination in-edge buckets; everything downstream is sparse.
// Timed call also includes ~1030us of harness reset (4 GiB ws poison +
// 1.07 GB adjacency restore) that we cannot control.
// R4 post-mortem: explicit prefetch pipeline regressed (+100us) — register
// rotation + twice-inlined slow path beat by plain grid-stride + 32 waves/CU.

constexpr int NN   = 16384;
constexpr int DIN  = 128;
constexpr int DOUT = 64;
constexpr float FXP_SCALE     = 65536.0f;
constexpr float FXP_INV_SCALE = 1.0f / 65536.0f;

// native clang vector: __builtin_nontemporal_load rejects HIP_vector_type
typedef uint32_t u32x4 __attribute__((ext_vector_type(4)));

__global__ void zero_u32(uint32_t* __restrict__ p, int n) {
    int i = blockIdx.x * blockDim.x + threadIdx.x;
    if (i < n) p[i] = 0u;
}

// Pass 1: stream adjacency once. 64 B/thread/iter: 4 independent nontemporal
// dwordx4 loads issued back-to-back, ONE any-test per 64 B. ~98.4% of
// iterations take the all-zero fast path (Poisson, p=0.001, 16 elems).
__global__ __launch_bounds__(256) void scan_adj(const u32x4* __restrict__ adj,
                                                uint32_t* __restrict__ row_cnt,
                                                uint32_t* __restrict__ col_cnt,
                                                uint32_t* __restrict__ bucket,
                                                int cap) {
    const uint32_t ngroups = (uint32_t)(NN / 16) * (uint32_t)NN;  // 16,777,216 x 64B
    const uint32_t stride  = gridDim.x * blockDim.x;              // 1,048,576
    for (uint32_t g = blockIdx.x * blockDim.x + threadIdx.x; g < ngroups; g += stride) {
        const u32x4* p = adj + 4 * (size_t)g;
        u32x4 c0 = __builtin_nontemporal_load(p + 0);
        u32x4 c1 = __builtin_nontemporal_load(p + 1);
        u32x4 c2 = __builtin_nontemporal_load(p + 2);
        u32x4 c3 = __builtin_nontemporal_load(p + 3);
        uint32_t any = (c0.x | c0.y | c0.z | c0.w) | (c1.x | c1.y | c1.z | c1.w)
                     | (c2.x | c2.y | c2.z | c2.w) | (c3.x | c3.y | c3.z | c3.w);
        if (__builtin_expect(any == 0u, 1)) continue;   // fast path
        uint32_t base = g << 4;                  // element index (16 per group)
        uint32_t row  = base >> 14;              // / 16384 (all 16 in one row)
        uint32_t col  = base & 16383u;           // % 16384
        uint32_t e[16] = { c0.x, c0.y, c0.z, c0.w, c1.x, c1.y, c1.z, c1.w,
                           c2.x, c2.y, c2.z, c2.w, c3.x, c3.y, c3.z, c3.w };
        uint32_t nz = 0;
        #pragma unroll
        for (int c = 0; c < 16; ++c) nz += (e[c] != 0u);
        atomicAdd(&row_cnt[row], nz);
        #pragma unroll
        for (int c = 0; c < 16; ++c) {
            if (e[c] != 0u) {
                uint32_t s = atomicAdd(&col_cnt[col + c], 1u);
                if (s < (uint32_t)cap)           // Poisson(16.4): cap=128 never hit
                    bucket[(size_t)(col + c) * (size_t)cap + s] = row;
            }
        }
    }
}

// Pass 2: sy[j,:] = colsum(j)^-1/2 * fxp(x[j,:] @ w).  w staged in LDS (32 KB);
// wsm[k*64+lane] is 2-way bank aliasing = free on gfx950.
__global__ __launch_bounds__(256) void xw_scale(const float* __restrict__ x,
                                                const float* __restrict__ w,
                                                const uint32_t* __restrict__ col_cnt,
                                                float* __restrict__ sy) {
    __shared__ float wsm[DIN * DOUT];   // 32 KB
    __shared__ float xs[4][DIN];        // 2 KB
    const float4* w4 = (const float4*)w;
    float4* wsm4 = (float4*)wsm;
    #pragma unroll
    for (int t = 0; t < (DIN * DOUT / 4) / 256; ++t)
        wsm4[t * 256 + threadIdx.x] = w4[t * 256 + threadIdx.x];
    int lane = threadIdx.x & 63;
    int sub  = threadIdx.x >> 6;
    int row  = blockIdx.x * 4 + sub;
    xs[sub][lane]      = x[row * DIN + lane];
    xs[sub][lane + 64] = x[row * DIN + lane + 64];
    __syncthreads();
    float acc = 0.0f;
    #pragma unroll
    for (int k = 0; k < DIN; ++k)
        acc = fmaf(xs[sub][k], wsm[k * DOUT + lane], acc);
    float yq = rintf(acc * FXP_SCALE) * FXP_INV_SCALE;   // round-half-even == np.round
    uint32_t c = col_cnt[row];
    if (c < 1u) c = 1u;                                  // clip(deg, 1)
    sy[row * DOUT + lane] = yq * rsqrtf((float)c);
}

// Pass 3: 4 destinations per 256-thread block, one wave each; lane d owns
// feature d. Gather unrolled x4 so four independent L2 loads are in flight.
__global__ __launch_bounds__(256) void aggregate(const float* __restrict__ sy,
                                                 const uint32_t* __restrict__ bucket,
                                                 const uint32_t* __restrict__ row_cnt,
                                                 const uint32_t* __restrict__ col_cnt,
                                                 const float* __restrict__ bias,
                                                 float* __restrict__ out,
                                                 int cap) {
    int sub = threadIdx.x >> 6;
    int d   = threadIdx.x & 63;
    int i   = blockIdx.x * 4 + sub;
    uint32_t cnt = col_cnt[i];
    if (cnt > (uint32_t)cap) cnt = (uint32_t)cap;
    const uint32_t* bk = bucket + (size_t)i * (size_t)cap;
    float acc = 0.0f;
    uint32_t s = 0;
    for (; s + 4 <= cnt; s += 4) {
        uint32_t j0 = bk[s], j1 = bk[s + 1], j2 = bk[s + 2], j3 = bk[s + 3];
        float a0 = sy[j0 * DOUT + d];
        float a1 = sy[j1 * DOUT + d];
        float a2 = sy[j2 * DOUT + d];
        float a3 = sy[j3 * DOUT + d];
        acc += (a0 + a1) + (a2 + a3);
    }
    for (; s < cnt; ++s) acc += sy[bk[s] * DOUT + d];
    uint32_t rc = row_cnt[i];
    if (rc < 1u) rc = 1u;                     // clip(deg, 1)
    float v = acc * rsqrtf((float)rc) + bias[d];
    out[i * DOUT + d] = rintf(v * FXP_SCALE) * FXP_INV_SCALE;
}

extern "C" void kernel_launch(void* const* d_in, const int* in_sizes, int n_in,
                              void* d_out, int out_size, void* d_ws, size_t ws_size,
                              hipStream_t stream) {
    const float* x    = (const float*)d_in[0];   // [16384,128]
    const float* adj  = (const float*)d_in[1];   // [16384,16384]
    const float* w    = (const float*)d_in[2];   // [128,64]
    const float* bias = (const float*)d_in[3];   // [1,64]
    float* out = (float*)d_out;                  // [16384,64] fp32

    // Workspace (poisoned 0xAA before every call -> zero counters each call):
    //   [0, 64K)  row_cnt u32[16384] | [64K,128K) col_cnt u32[16384]
    //   [128K, +4MB) sy f32[16384*64] | [rest) bucket u32[16384*cap]
    char* ws = (char*)d_ws;
    uint32_t* row_cnt = (uint32_t*)(ws);
    uint32_t* col_cnt = (uint32_t*)(ws + 65536);
    float*    sy      = (float*)(ws + 131072);
    size_t fixed = 131072 + (size_t)NN * DOUT * sizeof(float);
    uint32_t* bucket  = (uint32_t*)(ws + fixed);

    int cap = 128;  // ~7.8x mean in-degree 16.4; bucket = 8 MB
    if (ws_size > fixed) {
        size_t avail_cap = (ws_size - fixed) / ((size_t)NN * sizeof(uint32_t));
        if (avail_cap < (size_t)cap) cap = (int)avail_cap;
    }

    zero_u32<<<(2 * NN + 255) / 256, 256, 0, stream>>>(row_cnt, 2 * NN);
    scan_adj<<<4096, 256, 0, stream>>>((const u32x4*)adj, row_cnt, col_cnt, bucket, cap);
    xw_scale<<<NN / 4, 256, 0, stream>>>(x, w, col_cnt, sy);
    aggregate<<<NN / 4, 256, 0, stream>>>(sy, bucket, row_cnt, col_cnt, bias, out, cap);
}

// Round 6
// 1347.689 us; speedup vs baseline: 1.1162x; 1.1162x over previous
//
#include <hip/hip_runtime.h>
#include <stdint.h>

// GraphConv: out = fxp( Drow^-1/2 * A^T * (Dcol^-1/2-scaled fxp(x@w)) + b )
// A is a 16384x16384 dense 0/1 fp32 matrix, density 0.001 (~268K nonzeros).
// One streaming pass over A (1.073 GB, HBM floor ~171us) builds degrees +
// per-destination in-edge buckets; everything downstream is sparse.
// Timed call includes ~1030us of harness reset (4 GiB ws poison + 1.07 GB
// adjacency restore) we cannot control.
// R4/R5 post-mortem: 64 B *consecutive* per lane = 64 B lane-stride per load
// instruction = 4x requests per cache line -> regression. This version keeps
// every load instruction unit-stride across the wave (1 req/line) while
// holding 64 B/lane in flight: unroll x4 with loads spaced by the grid span.

constexpr int NN   = 16384;
constexpr int DIN  = 128;
constexpr int DOUT = 64;
constexpr float FXP_SCALE     = 65536.0f;
constexpr float FXP_INV_SCALE = 1.0f / 65536.0f;

// native clang vector: __builtin_nontemporal_load rejects HIP_vector_type
typedef uint32_t u32x4 __attribute__((ext_vector_type(4)));

__global__ void zero_u32(uint32_t* __restrict__ p, int n) {
    int i = blockIdx.x * blockDim.x + threadIdx.x;
    if (i < n) p[i] = 0u;
}

__device__ __forceinline__ void process_chunk(uint32_t idx, u32x4 v,
                                              uint32_t* __restrict__ row_cnt,
                                              uint32_t* __restrict__ col_cnt,
                                              uint32_t* __restrict__ bucket,
                                              int cap) {
    if ((v.x | v.y | v.z | v.w) == 0u) return;
    uint32_t base = idx << 2;                 // element index
    uint32_t row  = base >> 14;               // / 16384
    uint32_t col  = base & 16383u;            // % 16384 (4 consec cols, one row)
    uint32_t e[4] = { v.x, v.y, v.z, v.w };
    uint32_t nz = (e[0] != 0u) + (e[1] != 0u) + (e[2] != 0u) + (e[3] != 0u);
    atomicAdd(&row_cnt[row], nz);
    #pragma unroll
    for (int c = 0; c < 4; ++c) {
        if (e[c] != 0u) {
            uint32_t s = atomicAdd(&col_cnt[col + c], 1u);
            if (s < (uint32_t)cap)            // Poisson(16.4): cap=128 never hit
                bucket[(size_t)(col + c) * (size_t)cap + s] = row;
        }
    }
}

// Pass 1: stream adjacency once. Unroll x4 with the 4 dwordx4 loads spaced by
// the grid span S: each load instruction is unit-stride across the wave
// (64 lanes x 16 B contiguous = 1 KB, 1 request/line), 64 B/lane in flight,
// ONE combined test per 64 B. ~98.4% of iterations take the all-zero path.
__global__ __launch_bounds__(256) void scan_adj(const u32x4* __restrict__ adj,
                                                uint32_t* __restrict__ row_cnt,
                                                uint32_t* __restrict__ col_cnt,
                                                uint32_t* __restrict__ bucket,
                                                int cap) {
    const uint32_t total = (uint32_t)(NN / 4) * (uint32_t)NN;   // 67,108,864 uint4
    const uint32_t S     = gridDim.x * blockDim.x;              // 1,048,576
    for (uint32_t i = blockIdx.x * blockDim.x + threadIdx.x; i < total; i += 4 * S) {
        u32x4 c0 = __builtin_nontemporal_load(&adj[i]);
        u32x4 c1 = __builtin_nontemporal_load(&adj[i + S]);
        u32x4 c2 = __builtin_nontemporal_load(&adj[i + 2 * S]);
        u32x4 c3 = __builtin_nontemporal_load(&adj[i + 3 * S]);
        uint32_t any = (c0.x | c0.y | c0.z | c0.w) | (c1.x | c1.y | c1.z | c1.w)
                     | (c2.x | c2.y | c2.z | c2.w) | (c3.x | c3.y | c3.z | c3.w);
        if (__builtin_expect(any == 0u, 1)) continue;   // fast path
        process_chunk(i,         c0, row_cnt, col_cnt, bucket, cap);
        process_chunk(i + S,     c1, row_cnt, col_cnt, bucket, cap);
        process_chunk(i + 2 * S, c2, row_cnt, col_cnt, bucket, cap);
        process_chunk(i + 3 * S, c3, row_cnt, col_cnt, bucket, cap);
    }
}

// Pass 2: sy[j,:] = colsum(j)^-1/2 * fxp(x[j,:] @ w).  w staged in LDS (32 KB);
// wsm[k*64+lane] is 2-way bank aliasing = free on gfx950.
__global__ __launch_bounds__(256) void xw_scale(const float* __restrict__ x,
                                                const float* __restrict__ w,
                                                const uint32_t* __restrict__ col_cnt,
                                                float* __restrict__ sy) {
    __shared__ float wsm[DIN * DOUT];   // 32 KB
    __shared__ float xs[4][DIN];        // 2 KB
    const float4* w4 = (const float4*)w;
    float4* wsm4 = (float4*)wsm;
    #pragma unroll
    for (int t = 0; t < (DIN * DOUT / 4) / 256; ++t)
        wsm4[t * 256 + threadIdx.x] = w4[t * 256 + threadIdx.x];
    int lane = threadIdx.x & 63;
    int sub  = threadIdx.x >> 6;
    int row  = blockIdx.x * 4 + sub;
    xs[sub][lane]      = x[row * DIN + lane];
    xs[sub][lane + 64] = x[row * DIN + lane + 64];
    __syncthreads();
    float acc = 0.0f;
    #pragma unroll
    for (int k = 0; k < DIN; ++k)
        acc = fmaf(xs[sub][k], wsm[k * DOUT + lane], acc);
    float yq = rintf(acc * FXP_SCALE) * FXP_INV_SCALE;   // round-half-even == np.round
    uint32_t c = col_cnt[row];
    if (c < 1u) c = 1u;                                  // clip(deg, 1)
    sy[row * DOUT + lane] = yq * rsqrtf((float)c);
}

// Pass 3: 4 destinations per 256-thread block, one wave each; lane d owns
// feature d. Gather unrolled x4 so four independent L2 loads are in flight.
__global__ __launch_bounds__(256) void aggregate(const float* __restrict__ sy,
                                                 const uint32_t* __restrict__ bucket,
                                                 const uint32_t* __restrict__ row_cnt,
                                                 const uint32_t* __restrict__ col_cnt,
                                                 const float* __restrict__ bias,
                                                 float* __restrict__ out,
                                                 int cap) {
    int sub = threadIdx.x >> 6;
    int d   = threadIdx.x & 63;
    int i   = blockIdx.x * 4 + sub;
    uint32_t cnt = col_cnt[i];
    if (cnt > (uint32_t)cap) cnt = (uint32_t)cap;
    const uint32_t* bk = bucket + (size_t)i * (size_t)cap;
    float acc = 0.0f;
    uint32_t s = 0;
    for (; s + 4 <= cnt; s += 4) {
        uint32_t j0 = bk[s], j1 = bk[s + 1], j2 = bk[s + 2], j3 = bk[s + 3];
        float a0 = sy[j0 * DOUT + d];
        float a1 = sy[j1 * DOUT + d];
        float a2 = sy[j2 * DOUT + d];
        float a3 = sy[j3 * DOUT + d];
        acc += (a0 + a1) + (a2 + a3);
    }
    for (; s < cnt; ++s) acc += sy[bk[s] * DOUT + d];
    uint32_t rc = row_cnt[i];
    if (rc < 1u) rc = 1u;                     // clip(deg, 1)
    float v = acc * rsqrtf((float)rc) + bias[d];
    out[i * DOUT + d] = rintf(v * FXP_SCALE) * FXP_INV_SCALE;
}

extern "C" void kernel_launch(void* const* d_in, const int* in_sizes, int n_in,
                              void* d_out, int out_size, void* d_ws, size_t ws_size,
                              hipStream_t stream) {
    const float* x    = (const float*)d_in[0];   // [16384,128]
    const float* adj  = (const float*)d_in[1];   // [16384,16384]
    const float* w    = (const float*)d_in[2];   // [128,64]
    const float* bias = (const float*)d_in[3];   // [1,64]
    float* out = (float*)d_out;                  // [16384,64] fp32

    // Workspace (poisoned 0xAA before every call -> zero counters each call):
    //   [0, 64K)  row_cnt u32[16384] | [64K,128K) col_cnt u32[16384]
    //   [128K, +4MB) sy f32[16384*64] | [rest) bucket u32[16384*cap]
    char* ws = (char*)d_ws;
    uint32_t* row_cnt = (uint32_t*)(ws);
    uint32_t* col_cnt = (uint32_t*)(ws + 65536);
    float*    sy      = (float*)(ws + 131072);
    size_t fixed = 131072 + (size_t)NN * DOUT * sizeof(float);
    uint32_t* bucket  = (uint32_t*)(ws + fixed);

    int cap = 128;  // ~7.8x mean in-degree 16.4; bucket = 8 MB
    if (ws_size > fixed) {
        size_t avail_cap = (ws_size - fixed) / ((size_t)NN * sizeof(uint32_t));
        if (avail_cap < (size_t)cap) cap = (int)avail_cap;
    }

    zero_u32<<<(2 * NN + 255) / 256, 256, 0, stream>>>(row_cnt, 2 * NN);
    scan_adj<<<4096, 256, 0, stream>>>((const u32x4*)adj, row_cnt, col_cnt, bucket, cap);
    xw_scale<<<NN / 4, 256, 0, stream>>>(x, w, col_cnt, sy);
    aggregate<<<NN / 4, 256, 0, stream>>>(sy, bucket, row_cnt, col_cnt, bias, out, cap);
}

// Round 7
// 1345.678 us; speedup vs baseline: 1.1179x; 1.0015x over previous
//
#include <hip/hip_runtime.h>
#include <stdint.h>

// GraphConv: out = fxp( Drow^-1/2 * A^T * (Dcol^-1/2-scaled fxp(x@w)) + b )
// A is a 16384x16384 dense 0/1 fp32 matrix, density 0.001 (~268K nonzeros).
// One streaming pass over A (1.073 GB, HBM floor ~171us) builds degrees +
// per-destination in-edge buckets; everything downstream is sparse.
// Timed call includes ~1030us of harness reset (4 GiB ws poison + 1.07 GB
// adjacency restore) we cannot control; fills themselves run at ~80% peak.
// R4/R5 lesson: consecutive-per-lane loads = 4x requests/cache-line -> slow.
// R6 lesson (confirmed): grid-span-spaced unroll keeps every load instruction
// unit-stride across the wave (1 req/line) AND stacks bytes in flight -> best.
// R7: unroll x8 (128 B/lane in flight) — scan is latency-limited (~32 waves/CU
// x ~16 issue-cyc < ~900 cyc HBM latency); more outstanding loads per wave.

constexpr int NN   = 16384;
constexpr int DIN  = 128;
constexpr int DOUT = 64;
constexpr float FXP_SCALE     = 65536.0f;
constexpr float FXP_INV_SCALE = 1.0f / 65536.0f;

// native clang vector: __builtin_nontemporal_load rejects HIP_vector_type
typedef uint32_t u32x4 __attribute__((ext_vector_type(4)));

__global__ void zero_u32(uint32_t* __restrict__ p, int n) {
    int i = blockIdx.x * blockDim.x + threadIdx.x;
    if (i < n) p[i] = 0u;
}

__device__ __forceinline__ void process_chunk(uint32_t idx, u32x4 v,
                                              uint32_t* __restrict__ row_cnt,
                                              uint32_t* __restrict__ col_cnt,
                                              uint32_t* __restrict__ bucket,
                                              int cap) {
    if ((v.x | v.y | v.z | v.w) == 0u) return;
    uint32_t base = idx << 2;                 // element index
    uint32_t row  = base >> 14;               // / 16384
    uint32_t col  = base & 16383u;            // % 16384 (4 consec cols, one row)
    uint32_t e[4] = { v.x, v.y, v.z, v.w };
    uint32_t nz = (e[0] != 0u) + (e[1] != 0u) + (e[2] != 0u) + (e[3] != 0u);
    atomicAdd(&row_cnt[row], nz);
    #pragma unroll
    for (int c = 0; c < 4; ++c) {
        if (e[c] != 0u) {
            uint32_t s = atomicAdd(&col_cnt[col + c], 1u);
            if (s < (uint32_t)cap)            // Poisson(16.4): cap=128 never hit
                bucket[(size_t)(col + c) * (size_t)cap + s] = row;
        }
    }
}

// Pass 1: stream adjacency once. Unroll x8 with the 8 dwordx4 loads spaced by
// the grid span S: every load instruction is unit-stride across the wave
// (64 lanes x 16 B contiguous = 1 KB, 1 request/line), 128 B/lane in flight,
// ONE combined test per 128 B. ~96.8% of iterations take the all-zero path.
__global__ __launch_bounds__(256) void scan_adj(const u32x4* __restrict__ adj,
                                                uint32_t* __restrict__ row_cnt,
                                                uint32_t* __restrict__ col_cnt,
                                                uint32_t* __restrict__ bucket,
                                                int cap) {
    const uint32_t total = (uint32_t)(NN / 4) * (uint32_t)NN;   // 67,108,864 uint4
    const uint32_t S     = gridDim.x * blockDim.x;              // 1,048,576
    for (uint32_t i = blockIdx.x * blockDim.x + threadIdx.x; i < total; i += 8 * S) {
        u32x4 c0 = __builtin_nontemporal_load(&adj[i]);
        u32x4 c1 = __builtin_nontemporal_load(&adj[i + S]);
        u32x4 c2 = __builtin_nontemporal_load(&adj[i + 2 * S]);
        u32x4 c3 = __builtin_nontemporal_load(&adj[i + 3 * S]);
        u32x4 c4 = __builtin_nontemporal_load(&adj[i + 4 * S]);
        u32x4 c5 = __builtin_nontemporal_load(&adj[i + 5 * S]);
        u32x4 c6 = __builtin_nontemporal_load(&adj[i + 6 * S]);
        u32x4 c7 = __builtin_nontemporal_load(&adj[i + 7 * S]);
        uint32_t any = (c0.x | c0.y | c0.z | c0.w) | (c1.x | c1.y | c1.z | c1.w)
                     | (c2.x | c2.y | c2.z | c2.w) | (c3.x | c3.y | c3.z | c3.w)
                     | (c4.x | c4.y | c4.z | c4.w) | (c5.x | c5.y | c5.z | c5.w)
                     | (c6.x | c6.y | c6.z | c6.w) | (c7.x | c7.y | c7.z | c7.w);
        if (__builtin_expect(any == 0u, 1)) continue;   // fast path
        process_chunk(i,         c0, row_cnt, col_cnt, bucket, cap);
        process_chunk(i + S,     c1, row_cnt, col_cnt, bucket, cap);
        process_chunk(i + 2 * S, c2, row_cnt, col_cnt, bucket, cap);
        process_chunk(i + 3 * S, c3, row_cnt, col_cnt, bucket, cap);
        process_chunk(i + 4 * S, c4, row_cnt, col_cnt, bucket, cap);
        process_chunk(i + 5 * S, c5, row_cnt, col_cnt, bucket, cap);
        process_chunk(i + 6 * S, c6, row_cnt, col_cnt, bucket, cap);
        process_chunk(i + 7 * S, c7, row_cnt, col_cnt, bucket, cap);
    }
}

// Pass 2: sy[j,:] = colsum(j)^-1/2 * fxp(x[j,:] @ w).  w staged in LDS (32 KB);
// wsm[k*64+lane] is 2-way bank aliasing = free on gfx950.
__global__ __launch_bounds__(256) void xw_scale(const float* __restrict__ x,
                                                const float* __restrict__ w,
                                                const uint32_t* __restrict__ col_cnt,
                                                float* __restrict__ sy) {
    __shared__ float wsm[DIN * DOUT];   // 32 KB
    __shared__ float xs[4][DIN];        // 2 KB
    const float4* w4 = (const float4*)w;
    float4* wsm4 = (float4*)wsm;
    #pragma unroll
    for (int t = 0; t < (DIN * DOUT / 4) / 256; ++t)
        wsm4[t * 256 + threadIdx.x] = w4[t * 256 + threadIdx.x];
    int lane = threadIdx.x & 63;
    int sub  = threadIdx.x >> 6;
    int row  = blockIdx.x * 4 + sub;
    xs[sub][lane]      = x[row * DIN + lane];
    xs[sub][lane + 64] = x[row * DIN + lane + 64];
    __syncthreads();
    float acc = 0.0f;
    #pragma unroll
    for (int k = 0; k < DIN; ++k)
        acc = fmaf(xs[sub][k], wsm[k * DOUT + lane], acc);
    float yq = rintf(acc * FXP_SCALE) * FXP_INV_SCALE;   // round-half-even == np.round
    uint32_t c = col_cnt[row];
    if (c < 1u) c = 1u;                                  // clip(deg, 1)
    sy[row * DOUT + lane] = yq * rsqrtf((float)c);
}

// Pass 3: 4 destinations per 256-thread block, one wave each; lane d owns
// feature d. Gather unrolled x4 so four independent L2 loads are in flight.
__global__ __launch_bounds__(256) void aggregate(const float* __restrict__ sy,
                                                 const uint32_t* __restrict__ bucket,
                                                 const uint32_t* __restrict__ row_cnt,
                                                 const uint32_t* __restrict__ col_cnt,
                                                 const float* __restrict__ bias,
                                                 float* __restrict__ out,
                                                 int cap) {
    int sub = threadIdx.x >> 6;
    int d   = threadIdx.x & 63;
    int i   = blockIdx.x * 4 + sub;
    uint32_t cnt = col_cnt[i];
    if (cnt > (uint32_t)cap) cnt = (uint32_t)cap;
    const uint32_t* bk = bucket + (size_t)i * (size_t)cap;
    float acc = 0.0f;
    uint32_t s = 0;
    for (; s + 4 <= cnt; s += 4) {
        uint32_t j0 = bk[s], j1 = bk[s + 1], j2 = bk[s + 2], j3 = bk[s + 3];
        float a0 = sy[j0 * DOUT + d];
        float a1 = sy[j1 * DOUT + d];
        float a2 = sy[j2 * DOUT + d];
        float a3 = sy[j3 * DOUT + d];
        acc += (a0 + a1) + (a2 + a3);
    }
    for (; s < cnt; ++s) acc += sy[bk[s] * DOUT + d];
    uint32_t rc = row_cnt[i];
    if (rc < 1u) rc = 1u;                     // clip(deg, 1)
    float v = acc * rsqrtf((float)rc) + bias[d];
    out[i * DOUT + d] = rintf(v * FXP_SCALE) * FXP_INV_SCALE;
}

extern "C" void kernel_launch(void* const* d_in, const int* in_sizes, int n_in,
                              void* d_out, int out_size, void* d_ws, size_t ws_size,
                              hipStream_t stream) {
    const float* x    = (const float*)d_in[0];   // [16384,128]
    const float* adj  = (const float*)d_in[1];   // [16384,16384]
    const float* w    = (const float*)d_in[2];   // [128,64]
    const float* bias = (const float*)d_in[3];   // [1,64]
    float* out = (float*)d_out;                  // [16384,64] fp32

    // Workspace (poisoned 0xAA before every call -> zero counters each call):
    //   [0, 64K)  row_cnt u32[16384] | [64K,128K) col_cnt u32[16384]
    //   [128K, +4MB) sy f32[16384*64] | [rest) bucket u32[16384*cap]
    char* ws = (char*)d_ws;
    uint32_t* row_cnt = (uint32_t*)(ws);
    uint32_t* col_cnt = (uint32_t*)(ws + 65536);
    float*    sy      = (float*)(ws + 131072);
    size_t fixed = 131072 + (size_t)NN * DOUT * sizeof(float);
    uint32_t* bucket  = (uint32_t*)(ws + fixed);

    int cap = 128;  // ~7.8x mean in-degree 16.4; bucket = 8 MB
    if (ws_size > fixed) {
        size_t avail_cap = (ws_size - fixed) / ((size_t)NN * sizeof(uint32_t));
        if (avail_cap < (size_t)cap) cap = (int)avail_cap;
    }

    zero_u32<<<(2 * NN + 255) / 256, 256, 0, stream>>>(row_cnt, 2 * NN);
    scan_adj<<<4096, 256, 0, stream>>>((const u32x4*)adj, row_cnt, col_cnt, bucket, cap);
    xw_scale<<<NN / 4, 256, 0, stream>>>(x, w, col_cnt, sy);
    aggregate<<<NN / 4, 256, 0, stream>>>(sy, bucket, row_cnt, col_cnt, bias, out, cap);
}